// Round 12
// baseline (164.575 us; speedup 1.0000x reference)
//
#include <hip/hip_runtime.h>
#include <hip/hip_cooperative_groups.h>

namespace cg = cooperative_groups;

#define BSZ  8
#define LSEQ 2048
#define DM   256
#define NS   16
#define NC   32          // chunks along L
#define LC   (LSEQ/NC)   // 64 timesteps per chunk
#define TILE_FLOATS (LC * DM)               // 64 KB LDS tile
#define VEC_ROUNDS  (TILE_FLOATS / 4 / DM)  // 16 float4 ops per thread

// Lean cooperative single kernel (r4 retry with the spill fixed):
//   phase 1: stage x tile -> LDS (float4), local scan h0=0, store carry
//   grid.sync
//   phase 2: chunk-prefix per (b,n,d) job (32768 jobs / 65536 threads)
//   grid.sync
//   phase 3: seeded scan from the SAME LDS tile (persists), y in place,
//            float4 store.  x is read from HBM exactly once.
// No __launch_bounds__, no register x-cache: ~90 VGPR, no spill (r4 lesson).
// carry layout: [b][chunk][n][d]  (d contiguous -> coalesced)
__global__ void k_coop(
        const float* __restrict__ x,
        const float* __restrict__ A,
        const float* __restrict__ Bm,
        const float* __restrict__ Cm,
        const float* __restrict__ Dv,
        const float* __restrict__ delta,
        float* __restrict__ carry,
        float* __restrict__ y) {
    __shared__ float lx[TILE_FLOATS];
    const int d     = threadIdx.x;
    const int chunk = blockIdx.x & (NC - 1);
    const int b     = blockIdx.x / NC;
    const size_t tile_base = ((size_t)(b * LSEQ + chunk * LC)) * DM;

    {   // stage: 16 x (256 thr x 16 B) = 64 KB contiguous
        const float4* __restrict__ src = (const float4*)(x + tile_base);
        float4* dst = (float4*)lx;
#pragma unroll
        for (int r = 0; r < VEC_ROUNDS; ++r)
            dst[r * DM + d] = src[r * DM + d];
    }

    // coefficients overlap staging latency
    const float dt = 1.0f / (1.0f + expf(-delta[d]));
    float a[NS], bb[NS], cc[NS];
#pragma unroll
    for (int n = 0; n < NS; ++n) {
        const float An = A[d * NS + n];
        a[n]  = expf(dt * An);
        bb[n] = dt * Bm[d * NS + n];
        cc[n] = Cm[d * NS + n];
    }
    const float Dd = Dv[d];
    __syncthreads();

    // ---- phase 1: local scan (h0 = 0), store carry aggregate ----
    float h[NS];
#pragma unroll
    for (int n = 0; n < NS; ++n) h[n] = 0.0f;
#pragma unroll 4
    for (int t = 0; t < LC; ++t) {
        const float xv = lx[t * DM + d];
#pragma unroll
        for (int n = 0; n < NS; ++n) h[n] = fmaf(a[n], h[n], bb[n] * xv);
    }
    {
        float* cp = carry + ((size_t)(b * NC + chunk) * NS) * DM + d;
#pragma unroll
        for (int n = 0; n < NS; ++n) cp[(size_t)n * DM] = h[n];
    }

    __threadfence();                 // carry visible device-wide (r4 pattern: verified correct)
    cg::this_grid().sync();

    // ---- phase 2: chunk-prefix, one (b,n,d) job per thread ----
    const int tid = blockIdx.x * DM + threadIdx.x;
    if (tid < BSZ * NS * DM) {
        const int dd = tid & (DM - 1);
        const int n2 = (tid >> 8) & (NS - 1);
        const int b2 = tid >> 12;
        const float dt2 = 1.0f / (1.0f + expf(-delta[dd]));
        const float aL  = expf(dt2 * A[dd * NS + n2] * (float)LC);
        float run = 0.0f;
        float* cp2 = carry + (size_t)b2 * NC * NS * DM + (size_t)n2 * DM + dd;
#pragma unroll
        for (int j = 0; j < NC; ++j) {
            const size_t off = (size_t)j * NS * DM;
            const float c = cp2[off];
            cp2[off] = run;                 // state entering chunk j
            run = fmaf(aL, run, c);         // state leaving chunk j
        }
    }

    __threadfence();
    cg::this_grid().sync();

    // ---- phase 3: seeded scan from persistent LDS tile; y in place ----
    {
        const float* hp = carry + ((size_t)(b * NC + chunk) * NS) * DM + d;
#pragma unroll
        for (int n = 0; n < NS; ++n) h[n] = hp[(size_t)n * DM];
    }
#pragma unroll 4
    for (int t = 0; t < LC; ++t) {
        const float xv = lx[t * DM + d];
        float acc = Dd * xv;
#pragma unroll
        for (int n = 0; n < NS; ++n) {
            h[n] = fmaf(a[n], h[n], bb[n] * xv);
            acc  = fmaf(h[n], cc[n], acc);
        }
        lx[t * DM + d] = acc;    // slot (t,d) owned by thread d
    }
    __syncthreads();
    {
        float4* __restrict__ dst = (float4*)(y + tile_base);
        const float4* src = (const float4*)lx;
#pragma unroll
        for (int r = 0; r < VEC_ROUNDS; ++r)
            dst[r * DM + d] = src[r * DM + d];
    }
}

// ---------------------------------------------------------------------------
extern "C" void kernel_launch(void* const* d_in, const int* in_sizes, int n_in,
                              void* d_out, int out_size, void* d_ws, size_t ws_size,
                              hipStream_t stream) {
    const float* x     = (const float*)d_in[0];
    const float* A     = (const float*)d_in[1];
    const float* Bm    = (const float*)d_in[2];
    const float* Cm    = (const float*)d_in[3];
    const float* Dv    = (const float*)d_in[4];
    const float* delta = (const float*)d_in[5];
    float* y     = (float*)d_out;
    float* carry = (float*)d_ws;   // BSZ*NC*NS*DM*4 = 4.2 MiB scratch

    void* args[] = {(void*)&x, (void*)&A, (void*)&Bm, (void*)&Cm,
                    (void*)&Dv, (void*)&delta, (void*)&carry, (void*)&y};
    hipLaunchCooperativeKernel((void*)k_coop, dim3(BSZ * NC), dim3(DM),
                               args, 0, stream);
}

// Round 13
// 32.342 us; speedup vs baseline: 5.0886x; 5.0886x over previous
//
#include <hip/hip_runtime.h>

#define BSZ  8
#define LSEQ 2048
#define DM   256
#define NS   16
#define NC   64          // chunks along L (512 blocks -> 2 blocks/CU)
#define LC   (LSEQ/NC)   // 32 timesteps per chunk
#define TILE_FLOATS (LC * DM)               // 32 KB LDS tile
#define VEC_ROUNDS  (TILE_FLOATS / 4 / DM)  // 8 float4 ops per thread

// ---------------------------------------------------------------------------
// Kernel 1: per-(b,chunk) local scan, h0=0; emit carry aggregate.
// 32 KB LDS -> 2 blocks/CU co-resident: stage/scan/store phases of one block
// overlap the other's (r12 lesson: sync must be kernel boundaries; this round
// targets the intra-body phase serialization instead).
// carry layout: [b][chunk][n][d]  (d contiguous -> coalesced)
// ---------------------------------------------------------------------------
__global__ void k_local(
        const float* __restrict__ x,
        const float* __restrict__ A,
        const float* __restrict__ Bm,
        const float* __restrict__ delta,
        float* __restrict__ carry) {
    __shared__ float lx[TILE_FLOATS];
    const int d     = threadIdx.x;
    const int chunk = blockIdx.x & (NC - 1);
    const int b     = blockIdx.x / NC;

    {   // vectorized stage: 8 rounds x 256 thr x 16 B = 32 KB contiguous
        const float4* __restrict__ src =
            (const float4*)(x + ((size_t)(b * LSEQ + chunk * LC)) * DM);
        float4* dst = (float4*)lx;
#pragma unroll
        for (int r = 0; r < VEC_ROUNDS; ++r)
            dst[r * DM + d] = src[r * DM + d];
    }

    // coefficient transcendentals overlap staging latency
    const float dt = 1.0f / (1.0f + expf(-delta[d]));
    float a[NS], bb[NS];
#pragma unroll
    for (int n = 0; n < NS; ++n) {
        a[n]  = expf(dt * A[d * NS + n]);
        bb[n] = dt * Bm[d * NS + n];
    }
    __syncthreads();

    float h[NS];
#pragma unroll
    for (int n = 0; n < NS; ++n) h[n] = 0.0f;
#pragma unroll 4
    for (int t = 0; t < LC; ++t) {
        const float xv = lx[t * DM + d];
#pragma unroll
        for (int n = 0; n < NS; ++n) h[n] = fmaf(a[n], h[n], bb[n] * xv);
    }

    float* cp = carry + ((size_t)(b * NC + chunk) * NS) * DM + d;
#pragma unroll
    for (int n = 0; n < NS; ++n) cp[(size_t)n * DM] = h[n];
}

// ---------------------------------------------------------------------------
// Pass 2: per-(b,n,d) prefix over NC chunk carries, RESTRUCTURED as
// load-all (independent, all in flight) -> register chain -> store-all.
// One memory round-trip of latency instead of NC serial round-trips.
// Full unroll => all v[] indices static => registers (rule #20).
// ---------------------------------------------------------------------------
__global__ void k_prefix(
        const float* __restrict__ A,
        const float* __restrict__ delta,
        float* __restrict__ carry) {
    const int tid = blockIdx.x * 256 + threadIdx.x;   // 0 .. BSZ*NS*DM-1
    const int d = tid & (DM - 1);
    const int n = (tid >> 8) & (NS - 1);
    const int b = tid >> 12;

    const float dt = 1.0f / (1.0f + expf(-delta[d]));
    const float aL = expf(dt * A[d * NS + n] * (float)LC);

    float* cp = carry + (size_t)b * NC * NS * DM + (size_t)n * DM + d;

    float v[NC];
#pragma unroll
    for (int j = 0; j < NC; ++j) v[j] = cp[(size_t)j * NS * DM];

    float run = 0.0f;
#pragma unroll
    for (int j = 0; j < NC; ++j) {
        const float c = v[j];
        v[j] = run;                    // state entering chunk j
        run = fmaf(aL, run, c);        // state leaving chunk j
    }

#pragma unroll
    for (int j = 0; j < NC; ++j) cp[(size_t)j * NS * DM] = v[j];
}

// ---------------------------------------------------------------------------
// Pass 3: seeded replay. Entry-state loads issued FIRST (needed after the
// stage anyway), then x stage, coefficients, scan, y in place, float4 store.
// ---------------------------------------------------------------------------
__global__ void k_final(
        const float* __restrict__ x,
        const float* __restrict__ A,
        const float* __restrict__ Bm,
        const float* __restrict__ Cm,
        const float* __restrict__ Dv,
        const float* __restrict__ delta,
        const float* __restrict__ hin,
        float* __restrict__ y) {
    __shared__ float lt[TILE_FLOATS];
    const int d     = threadIdx.x;
    const int chunk = blockIdx.x & (NC - 1);
    const int b     = blockIdx.x / NC;

    // entry state: issue these 16 strided loads before anything else
    float h[NS];
    const float* hp = hin + ((size_t)(b * NC + chunk) * NS) * DM + d;
#pragma unroll
    for (int n = 0; n < NS; ++n) h[n] = hp[(size_t)n * DM];

    const size_t tile_base = ((size_t)(b * LSEQ + chunk * LC)) * DM;
    {   // vectorized stage of x tile
        const float4* __restrict__ src = (const float4*)(x + tile_base);
        float4* dst = (float4*)lt;
#pragma unroll
        for (int r = 0; r < VEC_ROUNDS; ++r)
            dst[r * DM + d] = src[r * DM + d];
    }

    const float dt = 1.0f / (1.0f + expf(-delta[d]));
    float a[NS], bb[NS], cc[NS];
#pragma unroll
    for (int n = 0; n < NS; ++n) {
        a[n]  = expf(dt * A[d * NS + n]);
        bb[n] = dt * Bm[d * NS + n];
        cc[n] = Cm[d * NS + n];
    }
    const float Dd = Dv[d];
    __syncthreads();

#pragma unroll 4
    for (int t = 0; t < LC; ++t) {
        const float xv = lt[t * DM + d];
        float acc = Dd * xv;
#pragma unroll
        for (int n = 0; n < NS; ++n) {
            h[n] = fmaf(a[n], h[n], bb[n] * xv);
            acc  = fmaf(h[n], cc[n], acc);
        }
        lt[t * DM + d] = acc;          // slot (t,d) owned by thread d
    }
    __syncthreads();

    {   // vectorized store of the y tile
        float4* __restrict__ dst = (float4*)(y + tile_base);
        const float4* src = (const float4*)lt;
#pragma unroll
        for (int r = 0; r < VEC_ROUNDS; ++r)
            dst[r * DM + d] = src[r * DM + d];
    }
}

// ---------------------------------------------------------------------------
extern "C" void kernel_launch(void* const* d_in, const int* in_sizes, int n_in,
                              void* d_out, int out_size, void* d_ws, size_t ws_size,
                              hipStream_t stream) {
    const float* x     = (const float*)d_in[0];
    const float* A     = (const float*)d_in[1];
    const float* Bm    = (const float*)d_in[2];
    const float* Cm    = (const float*)d_in[3];
    const float* Dv    = (const float*)d_in[4];
    const float* delta = (const float*)d_in[5];
    float* y = (float*)d_out;

    float* carry = (float*)d_ws;   // BSZ*NC*NS*DM*4 = 8.4 MiB scratch

    dim3 blk(DM);
    dim3 grd1(BSZ * NC);                 // 512 blocks -> 2 blocks/CU
    k_local<<<grd1, blk, 0, stream>>>(x, A, Bm, delta, carry);

    dim3 grd2((BSZ * NS * DM) / 256);    // 128 blocks
    k_prefix<<<grd2, dim3(256), 0, stream>>>(A, delta, carry);

    k_final<<<grd1, blk, 0, stream>>>(x, A, Bm, Cm, Dv, delta, carry, y);
}